// Round 4
// baseline (23.186 us; speedup 1.0000x reference)
//
#include <hip/hip_runtime.h>
#include <hip/hip_bf16.h>
#include <float.h>

// MeshLoss: out = mean_b,m( min_n |pc[b,m]-top[b,n]|^2 ) + mean((bottom-fem_bottom)^2)
// network_mesh (4,3,32,16,32) f32, pc (4,3,16384) f32, fem_mesh (4,3,32,16,32) f32.
// top[b,n] = network_mesh[b,:, n>>5, 15, n&31], n in [0,1024)
//
// |p-t|^2 = |p|^2 + (|t|^2 - 2 p.t): stage (tx,ty,tz,|t|^2) in LDS; per pair
// d' = fma(-2px,tx, fma(-2py,ty, fma(-2pz,tz, t2))) = 3 FMA, folded pairwise
// into v_min3_f32 -> 3.5 VALU inst/pair. |p|^2 added after the min.
//
// SINGLE fused compute kernel: 256 blocks x 512 threads (16 waves/CU = 2/SIMD).
//   block = (batch b, chunk of 256 pc points). All 1024 tops staged in LDS.
//   Threads t and t+256 process the same point over top halves [0,512)/[512,1024);
//   halves combine via one LDS min. fem MSE: 180 float4 per block (1/thread).
//   Block total -> one atomicAdd into out[0] (zeroed by a 4-byte memset node).

#define B_BATCH         4
#define NM_BATCH_STRIDE 49152     // 3*32*16*32 (== pc batch stride)
#define CH_STRIDE       16384
#define NTOP            1024
#define HALF_TOPS       512
#define FEM_VEC4        46080     // 184320/4
#define FEM_PER_BLK     180       // 46080 / 256
#define NBLK            256
#define NTHR            512

__global__ __launch_bounds__(NTHR, 4) void meshloss_fused(
    const float* __restrict__ nm,
    const float* __restrict__ pc,
    const float* __restrict__ fem,
    float* __restrict__ out)
{
    __shared__ float4 top[NTOP];    // 16 KB
    __shared__ float  sm[NTHR];     // 2 KB
    __shared__ float  wsum[8];

    const int t     = threadIdx.x;
    const int b     = blockIdx.x >> 6;     // batch
    const int chunk = blockIdx.x & 63;     // 256-point chunk within batch

    // ---- stage all 1024 tops (j==15 slice) with |t|^2 ----
    const float* nmb = nm + b * NM_BATCH_STRIDE;
    #pragma unroll
    for (int p0 = 0; p0 < NTOP; p0 += NTHR) {
        const int p = p0 + t;
        const int i = p >> 5, k = p & 31;
        const int base = i * 512 + 480 + k;          // (i*16+15)*32 + k
        float x = nmb[0 * CH_STRIDE + base];
        float y = nmb[1 * CH_STRIDE + base];
        float z = nmb[2 * CH_STRIDE + base];
        top[p] = make_float4(x, y, z, x * x + y * y + z * z);
    }
    __syncthreads();

    // ---- each point handled by two threads (top halves) ----
    const int pt   = t & 255;
    const int half = t >> 8;
    const int m    = chunk * 256 + pt;
    const float* pcb = pc + b * NM_BATCH_STRIDE;
    const float x = pcb[m];
    const float y = pcb[CH_STRIDE + m];
    const float z = pcb[2 * CH_STRIDE + m];
    const float pp  = x * x + y * y + z * z;
    const float px2 = -2.0f * x, py2 = -2.0f * y, pz2 = -2.0f * z;

    float mn = FLT_MAX;
    const float4* tp = top + half * HALF_TOPS;
    #pragma unroll 4
    for (int n = 0; n < HALF_TOPS; n += 4) {
        float4 T0 = tp[n + 0];
        float4 T1 = tp[n + 1];
        float4 T2 = tp[n + 2];
        float4 T3 = tp[n + 3];
        float d0 = __builtin_fmaf(px2, T0.x, __builtin_fmaf(py2, T0.y,
                   __builtin_fmaf(pz2, T0.z, T0.w)));
        float d1 = __builtin_fmaf(px2, T1.x, __builtin_fmaf(py2, T1.y,
                   __builtin_fmaf(pz2, T1.z, T1.w)));
        float d2 = __builtin_fmaf(px2, T2.x, __builtin_fmaf(py2, T2.y,
                   __builtin_fmaf(pz2, T2.z, T2.w)));
        float d3 = __builtin_fmaf(px2, T3.x, __builtin_fmaf(py2, T3.y,
                   __builtin_fmaf(pz2, T3.z, T3.w)));
        mn = fminf(mn, fminf(d0, d1));   // v_min3_f32
        mn = fminf(mn, fminf(d2, d3));   // v_min3_f32
    }
    sm[t] = mn;
    __syncthreads();

    // ---- combine halves + scale; fem term folded in ----
    float v = 0.0f;
    if (t < 256)
        v = (fminf(sm[t], sm[t + 256]) + pp) * (1.0f / 65536.0f);

    if (t < FEM_PER_BLK) {
        const int q   = blockIdx.x * FEM_PER_BLK + t;
        const int bci = q / 120;
        const int r   = q - bci * 120;
        const int s   = bci * 128 + r;
        float4 a = reinterpret_cast<const float4*>(nm)[s];
        float4 f = reinterpret_cast<const float4*>(fem)[s];
        float dx = a.x - f.x, dy = a.y - f.y, dz = a.z - f.z, dw = a.w - f.w;
        v += (dx * dx + dy * dy + dz * dz + dw * dw) * (1.0f / 184320.0f);
    }

    // ---- block reduce (8 waves) + one atomic per block ----
    for (int o = 32; o > 0; o >>= 1) v += __shfl_down(v, o, 64);
    if ((t & 63) == 0) wsum[t >> 6] = v;
    __syncthreads();
    if (t == 0) {
        float s = 0.0f;
        #pragma unroll
        for (int w = 0; w < 8; ++w) s += wsum[w];
        atomicAdd(out, s);
    }
}

extern "C" void kernel_launch(void* const* d_in, const int* in_sizes, int n_in,
                              void* d_out, int out_size, void* d_ws, size_t ws_size,
                              hipStream_t stream) {
    const float* nm  = (const float*)d_in[0];
    const float* pc  = (const float*)d_in[1];
    const float* fem = (const float*)d_in[2];
    float* out = (float*)d_out;

    hipMemsetAsync(out, 0, sizeof(float), stream);
    meshloss_fused<<<NBLK, NTHR, 0, stream>>>(nm, pc, fem, out);
}

// Round 5
// 18.579 us; speedup vs baseline: 1.2480x; 1.2480x over previous
//
#include <hip/hip_runtime.h>
#include <hip/hip_bf16.h>
#include <float.h>

// MeshLoss: out = mean_b,m( min_n |pc[b,m]-top[b,n]|^2 ) + mean((bottom-fem_bottom)^2)
// network_mesh (4,3,32,16,32) f32, pc (4,3,16384) f32, fem_mesh (4,3,32,16,32) f32.
// top[b,n] = network_mesh[b,:, n>>5, 15, n&31], n in [0,1024)
//
// |p-t|^2 = |p|^2 + (|t|^2 - 2 p.t): stage (tx,ty,tz,|t|^2) in LDS; per pair
// d' = fma(-2px,tx, fma(-2py,ty, fma(-2pz,tz, t2))) = 3 FMA, pairs folded via
// v_min3_f32 -> 3.5 VALU/pair. |p|^2 added at the tile-partial write.
//
// KEY SIZING (R4 post-mortem): LDS broadcast reads cost like distinct reads on
// the return path; wave-level ds_read_b128 count per CU = 4096/P. P=8 (T=64,
// 16 tiles) puts LDS (~6.1K cyc/CU) under the VALU floor (~7.2K cyc/CU).
//
// K1: 512 blocks x 256 thr = 4 batches x 8 pc-chunks(2048 pts) x 16 top-tiles(64).
//     P=8 points/thread. Tile partial mins (+|p|^2) -> ws[tile][65536] (4 MB).
//     Block 0 zeroes out[0] (K2 strictly after K1).
// K2: 256 blocks x 256 thr: per thread one point: 16-way tile min (L2-resident),
//     + fem MSE (threads < 46080 take one float4 pair), block-reduce, one
//     atomicAdd per block into out[0].

#define B_BATCH         4
#define MPTS            16384
#define NM_BATCH_STRIDE 49152     // 3*32*16*32 (== pc batch stride)
#define CH_STRIDE       16384

#define PC_PER_THREAD   8
#define PC_CHUNK        2048      // 256 threads * 8
#define N_CHUNKS        8
#define N_TILES         16
#define TILE_TOPS       64        // 1024 / 16

#define NUM_DIST_BLOCKS (B_BATCH * N_CHUNKS * N_TILES)   // 512
#define NUM_RED_BLOCKS  256

#define TOTAL_M         65536     // B*M
#define FEM_VEC4        46080     // 184320/4

__device__ __forceinline__ float block_reduce_sum(float v) {
    for (int o = 32; o > 0; o >>= 1) v += __shfl_down(v, o, 64);
    __shared__ float s[4];
    int lane = threadIdx.x & 63;
    int w    = threadIdx.x >> 6;
    if (lane == 0) s[w] = v;
    __syncthreads();
    if (threadIdx.x == 0) v = s[0] + s[1] + s[2] + s[3];
    return v;
}

__global__ __launch_bounds__(256) void meshloss_dist(
    const float* __restrict__ nm,
    const float* __restrict__ pc,
    float* __restrict__ ws,
    float* __restrict__ out)
{
    const int t   = threadIdx.x;
    const int bid = blockIdx.x;

    if (bid == 0 && t == 0) out[0] = 0.0f;   // K2 runs after K1: no race

    const int b     = bid >> 7;          // /128: batch
    const int rem   = bid & 127;
    const int chunk = rem >> 4;          // 8 pc chunks of 2048
    const int tile  = rem & 15;          // 16 top tiles of 64

    __shared__ float4 top[TILE_TOPS];    // 1 KB
    const float* nmb = nm + b * NM_BATCH_STRIDE;
    if (t < TILE_TOPS) {
        const int p = tile * TILE_TOPS + t;
        const int i = p >> 5, k = p & 31;
        const int base = i * 512 + 480 + k;     // (i*16+15)*32 + k
        float x = nmb[0 * CH_STRIDE + base];
        float y = nmb[1 * CH_STRIDE + base];
        float z = nmb[2 * CH_STRIDE + base];
        top[t] = make_float4(x, y, z, x * x + y * y + z * z);
    }
    __syncthreads();

    const float* pcb = pc + b * NM_BATCH_STRIDE;
    const int mbase = chunk * PC_CHUNK + t;

    float px2[PC_PER_THREAD], py2[PC_PER_THREAD], pz2[PC_PER_THREAD];
    float pp[PC_PER_THREAD], mn[PC_PER_THREAD];
    #pragma unroll
    for (int j = 0; j < PC_PER_THREAD; ++j) {
        const int m = mbase + j * 256;
        float x = pcb[m];
        float y = pcb[CH_STRIDE + m];
        float z = pcb[2 * CH_STRIDE + m];
        pp[j]  = x * x + y * y + z * z;
        px2[j] = -2.0f * x;
        py2[j] = -2.0f * y;
        pz2[j] = -2.0f * z;
        mn[j]  = FLT_MAX;
    }

    for (int n = 0; n < TILE_TOPS; n += 4) {
        float4 T0 = top[n + 0];
        float4 T1 = top[n + 1];
        float4 T2 = top[n + 2];
        float4 T3 = top[n + 3];
        #pragma unroll
        for (int j = 0; j < PC_PER_THREAD; ++j) {
            float d0 = __builtin_fmaf(px2[j], T0.x,
                       __builtin_fmaf(py2[j], T0.y,
                       __builtin_fmaf(pz2[j], T0.z, T0.w)));
            float d1 = __builtin_fmaf(px2[j], T1.x,
                       __builtin_fmaf(py2[j], T1.y,
                       __builtin_fmaf(pz2[j], T1.z, T1.w)));
            float d2 = __builtin_fmaf(px2[j], T2.x,
                       __builtin_fmaf(py2[j], T2.y,
                       __builtin_fmaf(pz2[j], T2.z, T2.w)));
            float d3 = __builtin_fmaf(px2[j], T3.x,
                       __builtin_fmaf(py2[j], T3.y,
                       __builtin_fmaf(pz2[j], T3.z, T3.w)));
            mn[j] = fminf(mn[j], fminf(d0, d1));   // v_min3_f32
            mn[j] = fminf(mn[j], fminf(d2, d3));   // v_min3_f32
        }
    }

    float* wrow = ws + tile * TOTAL_M + b * MPTS;
    #pragma unroll
    for (int j = 0; j < PC_PER_THREAD; ++j)
        wrow[mbase + j * 256] = mn[j] + pp[j];
}

__global__ __launch_bounds__(256) void meshloss_reduce(
    const float* __restrict__ ws,
    const float* __restrict__ nm,
    const float* __restrict__ fem,
    float* __restrict__ out)
{
    const int gid = blockIdx.x * 256 + threadIdx.x;   // 0..65535

    // ---- dist: min over 16 tile partials (coalesced, L2-resident) ----
    float v = ws[gid];
    #pragma unroll
    for (int tl = 1; tl < N_TILES; ++tl)
        v = fminf(v, ws[tl * TOTAL_M + gid]);
    float acc = v * (1.0f / 65536.0f);

    // ---- fem MSE: one float4 pair for threads < 46080 ----
    if (gid < FEM_VEC4) {
        const int bci = gid / 120;
        const int r   = gid - bci * 120;
        const int s   = bci * 128 + r;
        float4 a = reinterpret_cast<const float4*>(nm)[s];
        float4 f = reinterpret_cast<const float4*>(fem)[s];
        float dx = a.x - f.x, dy = a.y - f.y, dz = a.z - f.z, dw = a.w - f.w;
        acc += (dx * dx + dy * dy + dz * dz + dw * dw) * (1.0f / 184320.0f);
    }

    float s = block_reduce_sum(acc);
    if (threadIdx.x == 0) atomicAdd(out, s);
}

extern "C" void kernel_launch(void* const* d_in, const int* in_sizes, int n_in,
                              void* d_out, int out_size, void* d_ws, size_t ws_size,
                              hipStream_t stream) {
    const float* nm  = (const float*)d_in[0];
    const float* pc  = (const float*)d_in[1];
    const float* fem = (const float*)d_in[2];
    float* out = (float*)d_out;
    float* ws  = (float*)d_ws;

    meshloss_dist<<<NUM_DIST_BLOCKS, 256, 0, stream>>>(nm, pc, ws, out);
    meshloss_reduce<<<NUM_RED_BLOCKS, 256, 0, stream>>>(ws, nm, fem, out);
}